// Round 5
// baseline (546.543 us; speedup 1.0000x reference)
//
#include <hip/hip_runtime.h>
#include <hip/hip_bf16.h>
#include <cstdint>
#include <cstddef>

// ---------------- types ----------------
typedef float f32x4v __attribute__((ext_vector_type(4)));
typedef __bf16 bf16x8 __attribute__((ext_vector_type(8)));
typedef unsigned short u16x4 __attribute__((ext_vector_type(4)));

#define GAS1(p) ((__attribute__((address_space(1))) void*)(p))
#define LAS3(p) ((__attribute__((address_space(3))) void*)(p))

// B=4, S=4096, D=H=1024. M = B*S = 16384.
// AB layout: [M][1024] packed fp16 pairs: lo16 = a = 1-sigmoid(k), hi16 = b = sigmoid(k)*g(th).
// Scan: NC=128 chunks of CL=32 steps per sequence (S=4096).
#define NC 128
#define CL 32

// ---------------- fp32 -> bf16 conversion ----------------
__global__ void cvt_f32_bf16(const float* __restrict__ src,
                             unsigned short* __restrict__ dst, int n4) {
  int i = blockIdx.x * blockDim.x + threadIdx.x;
  if (i >= n4) return;
  float4 v = reinterpret_cast<const float4*>(src)[i];
  u16x4 o;
  o[0] = __builtin_bit_cast(unsigned short, (__bf16)v.x);
  o[1] = __builtin_bit_cast(unsigned short, (__bf16)v.y);
  o[2] = __builtin_bit_cast(unsigned short, (__bf16)v.z);
  o[3] = __builtin_bit_cast(unsigned short, (__bf16)v.w);
  reinterpret_cast<u16x4*>(dst)[i] = o;
}

// two fp32 sources -> one contiguous bf16 dest (Wz then Wh), n4h float4s each
__global__ void cvt_pair_bf16(const float* __restrict__ s0, const float* __restrict__ s1,
                              unsigned short* __restrict__ dst, int n4h) {
  int i = blockIdx.x * blockDim.x + threadIdx.x;
  if (i >= 2 * n4h) return;
  const float* s = (i < n4h) ? s0 : s1;
  int j = (i < n4h) ? i : i - n4h;
  float4 v = reinterpret_cast<const float4*>(s)[j];
  u16x4 o;
  o[0] = __builtin_bit_cast(unsigned short, (__bf16)v.x);
  o[1] = __builtin_bit_cast(unsigned short, (__bf16)v.y);
  o[2] = __builtin_bit_cast(unsigned short, (__bf16)v.z);
  o[3] = __builtin_bit_cast(unsigned short, (__bf16)v.w);
  reinterpret_cast<u16x4*>(dst)[i] = o;
}

// ---------------- fused GEMM: k and th tiles for the SAME channels, epilogue -> (a,b) fp16 ----------------
// A: [M][1024] bf16. W: [2048][1024] bf16 (rows 0..1023 = Wz, 1024..2047 = Wh).
// Each block: 128 rows x 128 channels; computes z-pre (A*Wz^T) AND h-pre (A*Wh^T),
// applies gate math, writes packed (a,b) fp16 into AB[M][1024] (4 B/elem).
__global__ __launch_bounds__(256) void gemm_fused(
    const __bf16* __restrict__ A, const __bf16* __restrict__ W,
    const float* __restrict__ bzv, const float* __restrict__ bhv,
    unsigned int* __restrict__ AB) {
  __shared__ __bf16 Als[128 * 32];
  __shared__ __bf16 Zls[128 * 32];
  __shared__ __bf16 Hls[128 * 32];
  const int tid = threadIdx.x;
  const int w = tid >> 6, l = tid & 63;
  const int bm = blockIdx.x, bn = blockIdx.y;   // bn in 0..7 (channel tiles)
  const int wr = w >> 1, wc = w & 1;

  f32x4v accz[4][4] = {};
  f32x4v acch[4][4] = {};

  // staging: thread i loads 16B; LDS dest linear in tid (gload_lds constraint)
  const int r0 = tid >> 2;
  const int c0 = (tid & 3) * 8;
  const __bf16* ga0 = A + (size_t)(bm * 128 + r0) * 1024 + c0;
  const __bf16* ga1 = ga0 + (size_t)64 * 1024;
  const __bf16* gz0 = W + (size_t)(bn * 128 + r0) * 1024 + c0;
  const __bf16* gz1 = gz0 + (size_t)64 * 1024;
  const __bf16* gh0 = gz0 + (size_t)1024 * 1024;   // Wh rows start at 1024
  const __bf16* gh1 = gh0 + (size_t)64 * 1024;
  __bf16* lsA0 = Als + w * 512;
  __bf16* lsA1 = Als + 2048 + w * 512;
  __bf16* lsZ0 = Zls + w * 512;
  __bf16* lsZ1 = Zls + 2048 + w * 512;
  __bf16* lsH0 = Hls + w * 512;
  __bf16* lsH1 = Hls + 2048 + w * 512;

  const int lr = l & 15, lk = (l >> 4) * 8;

  for (int kt = 0; kt < 32; ++kt) {
    const int ko = kt * 32;
    __builtin_amdgcn_global_load_lds(GAS1(ga0 + ko), LAS3(lsA0), 16, 0, 0);
    __builtin_amdgcn_global_load_lds(GAS1(ga1 + ko), LAS3(lsA1), 16, 0, 0);
    __builtin_amdgcn_global_load_lds(GAS1(gz0 + ko), LAS3(lsZ0), 16, 0, 0);
    __builtin_amdgcn_global_load_lds(GAS1(gz1 + ko), LAS3(lsZ1), 16, 0, 0);
    __builtin_amdgcn_global_load_lds(GAS1(gh0 + ko), LAS3(lsH0), 16, 0, 0);
    __builtin_amdgcn_global_load_lds(GAS1(gh1 + ko), LAS3(lsH1), 16, 0, 0);
    asm volatile("s_waitcnt vmcnt(0)" ::: "memory");
    __syncthreads();

    bf16x8 af[4], zf[4], hf[4];
#pragma unroll
    for (int f = 0; f < 4; ++f) {
      af[f] = *reinterpret_cast<const bf16x8*>(Als + (wr * 64 + f * 16 + lr) * 32 + lk);
      zf[f] = *reinterpret_cast<const bf16x8*>(Zls + (wc * 64 + f * 16 + lr) * 32 + lk);
      hf[f] = *reinterpret_cast<const bf16x8*>(Hls + (wc * 64 + f * 16 + lr) * 32 + lk);
    }
#pragma unroll
    for (int m = 0; m < 4; ++m)
#pragma unroll
      for (int n = 0; n < 4; ++n) {
        accz[m][n] = __builtin_amdgcn_mfma_f32_16x16x32_bf16(af[m], zf[n], accz[m][n], 0, 0, 0);
        acch[m][n] = __builtin_amdgcn_mfma_f32_16x16x32_bf16(af[m], hf[n], acch[m][n], 0, 0, 0);
      }
    __syncthreads();
  }

  // C/D layout (m89-verified): col = lane&15, row = (lane>>4)*4 + reg
  const int lg = l >> 4;
#pragma unroll
  for (int m = 0; m < 4; ++m) {
    const int row = bm * 128 + wr * 64 + m * 16 + lg * 4;
#pragma unroll
    for (int n = 0; n < 4; ++n) {
      const int col = bn * 128 + wc * 64 + n * 16 + lr;   // channel 0..1023
      const float kb = bzv[col];
      const float tb = bhv[col];
#pragma unroll
      for (int r = 0; r < 4; ++r) {
        float k = accz[m][n][r] + kb;
        float t = acch[m][n][r] + tb;
        float ek = __expf(k);
        float a = 1.0f / (1.0f + ek);        // 1 - sigmoid(k)
        float z = 1.0f - a;
        float g = (t >= 0.0f) ? (t + 0.5f) : (1.0f / (1.0f + __expf(-t)));
        float bq = z * g;
        unsigned short ha = __builtin_bit_cast(unsigned short, (_Float16)a);
        unsigned short hb = __builtin_bit_cast(unsigned short, (_Float16)bq);
        AB[(size_t)(row + r) * 1024 + col] = ((unsigned int)hb << 16) | (unsigned int)ha;
      }
    }
  }
}

// ---------------- scan passes (pure fp16-unpack + FMA, 1 thread per channel) ----------------
__device__ __forceinline__ void unpack_ab(unsigned int v, float& a, float& b) {
  a = (float)__builtin_bit_cast(_Float16, (unsigned short)(v & 0xffffu));
  b = (float)__builtin_bit_cast(_Float16, (unsigned short)(v >> 16));
}

// Pass 1: per-chunk summary. 524288 threads: t -> ch (0..4095), c (0..NC-1).
__global__ void pass1_summary(const unsigned int* __restrict__ AB,
                              float* __restrict__ SA, float* __restrict__ SB) {
  int t = blockIdx.x * 256 + threadIdx.x;
  int ch = t & 4095, c = t >> 12;
  int bb = ch >> 10, hch = ch & 1023;
  const unsigned int* p = AB + (size_t)(bb * 4096 + c * CL) * 1024 + hch;
  float A = 1.0f, L = 0.0f;
#pragma unroll 8
  for (int i = 0; i < CL; ++i) {
    float a, b;
    unpack_ab(p[(size_t)i * 1024], a, b);
    A *= a;
    L = a * L + b;
  }
  SA[c * 4096 + ch] = A;
  SB[c * 4096 + ch] = L;
}

// Pass 2: sequential scan over NC chunk summaries; emits h entering each chunk.
__global__ void pass2_chunkscan(const float* __restrict__ SA, const float* __restrict__ SB,
                                float* __restrict__ Hin) {
  int ch = blockIdx.x * 256 + threadIdx.x;    // 4096 threads
  float h = 0.5f;                              // h_0 = g(0) = 0.5
  for (int c = 0; c < NC; ++c) {
    Hin[c * 4096 + ch] = h;
    h = SA[c * 4096 + ch] * h + SB[c * 4096 + ch];
  }
}

// Pass 3: re-walk chunk with correct h_in, emit h.
// MODE 0: bf16 h1 (layer-2 GEMM input) + fp32 h_n row. MODE 1: fp32 h2 to d_out + h_n row.
template <int MODE>
__global__ void pass3_emit(const unsigned int* __restrict__ AB, const float* __restrict__ Hin,
                           unsigned short* __restrict__ h1b, float* __restrict__ out,
                           float* __restrict__ hn) {
  int t = blockIdx.x * 256 + threadIdx.x;
  int ch = t & 4095, c = t >> 12;
  int bb = ch >> 10, hch = ch & 1023;
  const unsigned int* p = AB + (size_t)(bb * 4096 + c * CL) * 1024 + hch;
  float h = Hin[c * 4096 + ch];
#pragma unroll 8
  for (int i = 0; i < CL; ++i) {
    float a, b;
    unpack_ab(p[(size_t)i * 1024], a, b);
    h = a * h + b;
    size_t row = (size_t)(bb * 4096 + c * CL + i);
    if (MODE == 0) {
      h1b[row * 1024 + hch] = __builtin_bit_cast(unsigned short, (__bf16)h);
    } else {
      out[row * 1024 + hch] = h;
    }
  }
  if (c == NC - 1) hn[bb * 1024 + hch] = h;   // h at s = S-1
}

// ---------------- launcher ----------------
extern "C" void kernel_launch(void* const* d_in, const int* in_sizes, int n_in,
                              void* d_out, int out_size, void* d_ws, size_t ws_size,
                              hipStream_t stream) {
  const float* x   = (const float*)d_in[0];
  const float* Wz0 = (const float*)d_in[1];
  const float* bz0 = (const float*)d_in[2];
  const float* Wh0 = (const float*)d_in[3];
  const float* bh0 = (const float*)d_in[4];
  const float* Wz1 = (const float*)d_in[5];
  const float* bz1 = (const float*)d_in[6];
  const float* Wh1 = (const float*)d_in[7];
  const float* bh1 = (const float*)d_in[8];
  float* out = (float*)d_out;

  char* ws = (char*)d_ws;
  unsigned int* AB  = (unsigned int*)(ws);              // 16384*1024*4 = 64 MB
  __bf16*       XB  = (__bf16*)(ws + 67108864);         // 32 MB (x bf16, then h1 bf16)
  __bf16*       WC0 = (__bf16*)(ws + 100663296);        // 4 MB
  __bf16*       WC1 = (__bf16*)(ws + 104857600);        // 4 MB
  float*        SA  = (float*)(ws + 109051904);         // NC*4096*4 = 2 MB
  float*        SB  = (float*)(ws + 111149056);         // 2 MB
  float*        Hin = (float*)(ws + 113246208);         // 2 MB

  float* hn0 = out + 16777216;          // h_n[0] = h1[:, -1, :]
  float* hn1 = out + 16777216 + 4096;   // h_n[1] = h2[:, -1, :]

  // conversions to bf16
  cvt_f32_bf16<<<16384, 256, 0, stream>>>(x, (unsigned short*)XB, 4194304);
  cvt_pair_bf16<<<2048, 256, 0, stream>>>(Wz0, Wh0, (unsigned short*)WC0, 262144);
  cvt_pair_bf16<<<2048, 256, 0, stream>>>(Wz1, Wh1, (unsigned short*)WC1, 262144);

  // ---- layer 1 ----
  gemm_fused<<<dim3(128, 8), 256, 0, stream>>>(XB, WC0, bz0, bh0, AB);
  pass1_summary<<<2048, 256, 0, stream>>>(AB, SA, SB);
  pass2_chunkscan<<<16, 256, 0, stream>>>(SA, SB, Hin);
  pass3_emit<0><<<2048, 256, 0, stream>>>(AB, Hin, (unsigned short*)XB, nullptr, hn0);

  // ---- layer 2 ----
  gemm_fused<<<dim3(128, 8), 256, 0, stream>>>(XB, WC1, bz1, bh1, AB);
  pass1_summary<<<2048, 256, 0, stream>>>(AB, SA, SB);
  pass2_chunkscan<<<16, 256, 0, stream>>>(SA, SB, Hin);
  pass3_emit<1><<<2048, 256, 0, stream>>>(AB, Hin, nullptr, out, hn1);
}

// Round 6
// 391.658 us; speedup vs baseline: 1.3955x; 1.3955x over previous
//
#include <hip/hip_runtime.h>
#include <hip/hip_bf16.h>
#include <cstdint>
#include <cstddef>

// ---------------- types ----------------
typedef float f32x4v __attribute__((ext_vector_type(4)));
typedef __bf16 bf16x8 __attribute__((ext_vector_type(8)));
typedef unsigned short u16x4 __attribute__((ext_vector_type(4)));

#define GAS1(p) ((__attribute__((address_space(1))) void*)(p))
#define LAS3(p) ((__attribute__((address_space(3))) void*)(p))

// B=4, S=4096, D=H=1024. M = B*S = 16384.
// WC layout: [2048][1024] bf16, row 2n = Wz row n, row 2n+1 = Wh row n (interleaved).
// GEMM output col 2n = k (z-pre) for channel n, col 2n+1 = th (h-pre) for channel n.
// AB layout: [M][1024] packed fp16 pairs: lo16 = a = 1-sigmoid(k), hi16 = b = sigmoid(k)*g(th).
// Scan: NC=64 chunks of CL=64 steps per sequence (S=4096).
#define NC 64
#define CL 64

// ---------------- fp32 -> bf16 conversion ----------------
__global__ void cvt_f32_bf16(const float* __restrict__ src,
                             unsigned short* __restrict__ dst, int n4) {
  int i = blockIdx.x * blockDim.x + threadIdx.x;
  if (i >= n4) return;
  float4 v = reinterpret_cast<const float4*>(src)[i];
  u16x4 o;
  o[0] = __builtin_bit_cast(unsigned short, (__bf16)v.x);
  o[1] = __builtin_bit_cast(unsigned short, (__bf16)v.y);
  o[2] = __builtin_bit_cast(unsigned short, (__bf16)v.z);
  o[3] = __builtin_bit_cast(unsigned short, (__bf16)v.w);
  reinterpret_cast<u16x4*>(dst)[i] = o;
}

// Wz/Wh -> row-interleaved bf16 WC: row 2n = Wz[n], row 2n+1 = Wh[n]
__global__ void cvt_w_interleave(const float* __restrict__ Wz, const float* __restrict__ Wh,
                                 unsigned short* __restrict__ dst) {
  int i = blockIdx.x * 256 + threadIdx.x;   // 2048 rows * 256 float4/row = 524288
  int row = i >> 8, c4 = i & 255;
  const float* src = (row & 1) ? Wh : Wz;
  float4 v = reinterpret_cast<const float4*>(src + (size_t)(row >> 1) * 1024)[c4];
  u16x4 o;
  o[0] = __builtin_bit_cast(unsigned short, (__bf16)v.x);
  o[1] = __builtin_bit_cast(unsigned short, (__bf16)v.y);
  o[2] = __builtin_bit_cast(unsigned short, (__bf16)v.z);
  o[3] = __builtin_bit_cast(unsigned short, (__bf16)v.w);
  reinterpret_cast<u16x4*>(dst)[(size_t)row * 256 + c4] = o;
}

// ---------------- bf16 MFMA GEMM (m97/round-3 structure) + fused gate epilogue ----------------
// A: [M][1024] bf16. WC: [2048][1024] bf16 interleaved. Output: AB [M][1024] u32 (a,b fp16).
// 128x128 tile, 4 waves (2x2 quadrants of 64x64), BK=32, acc[4][4] only.
__global__ __launch_bounds__(256) void gemm_ab(
    const __bf16* __restrict__ A, const __bf16* __restrict__ Bw,
    const float* __restrict__ bzv, const float* __restrict__ bhv,
    unsigned int* __restrict__ AB) {
  __shared__ __bf16 Als[128 * 32];
  __shared__ __bf16 Bls[128 * 32];
  const int tid = threadIdx.x;
  const int w = tid >> 6, l = tid & 63;
  const int bm = blockIdx.x, bn = blockIdx.y;   // bn 0..15
  const int wr = w >> 1, wc = w & 1;

  f32x4v acc[4][4] = {};

  const int r0 = tid >> 2;
  const int c0 = (tid & 3) * 8;
  const __bf16* ga0 = A + (size_t)(bm * 128 + r0) * 1024 + c0;
  const __bf16* ga1 = ga0 + (size_t)64 * 1024;
  const __bf16* gb0 = Bw + (size_t)(bn * 128 + r0) * 1024 + c0;
  const __bf16* gb1 = gb0 + (size_t)64 * 1024;
  __bf16* lsA0 = Als + w * 512;
  __bf16* lsA1 = Als + 2048 + w * 512;
  __bf16* lsB0 = Bls + w * 512;
  __bf16* lsB1 = Bls + 2048 + w * 512;

  const int lr = l & 15, lk = (l >> 4) * 8;

  for (int kt = 0; kt < 32; ++kt) {
    const int ko = kt * 32;
    __builtin_amdgcn_global_load_lds(GAS1(ga0 + ko), LAS3(lsA0), 16, 0, 0);
    __builtin_amdgcn_global_load_lds(GAS1(ga1 + ko), LAS3(lsA1), 16, 0, 0);
    __builtin_amdgcn_global_load_lds(GAS1(gb0 + ko), LAS3(lsB0), 16, 0, 0);
    __builtin_amdgcn_global_load_lds(GAS1(gb1 + ko), LAS3(lsB1), 16, 0, 0);
    asm volatile("s_waitcnt vmcnt(0)" ::: "memory");
    __syncthreads();

    bf16x8 af[4], bv[4];
#pragma unroll
    for (int f = 0; f < 4; ++f) {
      af[f] = *reinterpret_cast<const bf16x8*>(Als + (wr * 64 + f * 16 + lr) * 32 + lk);
      bv[f] = *reinterpret_cast<const bf16x8*>(Bls + (wc * 64 + f * 16 + lr) * 32 + lk);
    }
#pragma unroll
    for (int m = 0; m < 4; ++m)
#pragma unroll
      for (int n = 0; n < 4; ++n)
        acc[m][n] = __builtin_amdgcn_mfma_f32_16x16x32_bf16(af[m], bv[n], acc[m][n], 0, 0, 0);
    __syncthreads();
  }

  // Epilogue: C/D layout col = lane&15, row = (lane>>4)*4 + reg (m89-verified).
  // col even = k for channel col/2, col odd = th for same channel (W row-interleave).
  // Adjacent lanes hold the (k, th) pair -> shfl_xor(.,1) exchange.
  const int lg = l >> 4;
  const bool evenLane = (l & 1) == 0;
#pragma unroll
  for (int m = 0; m < 4; ++m) {
    const int row = bm * 128 + wr * 64 + m * 16 + lg * 4;
#pragma unroll
    for (int n = 0; n < 4; ++n) {
      const int col = bn * 128 + wc * 64 + n * 16 + lr;
      const int ch = col >> 1;                        // global channel 0..1023
      const float bias = (col & 1) ? bhv[ch] : bzv[ch];
      float v0 = acc[m][n][0] + bias;
      float v1 = acc[m][n][1] + bias;
      float v2 = acc[m][n][2] + bias;
      float v3 = acc[m][n][3] + bias;
      float e0 = __shfl_xor(v0, 1, 64);
      float e1 = __shfl_xor(v1, 1, 64);
      float e2 = __shfl_xor(v2, 1, 64);
      float e3 = __shfl_xor(v3, 1, 64);
      // even lane: gates for rows r=0,1 (k=own, th=partner)
      // odd  lane: gates for rows r=2,3 (k=partner, th=own)
      float k0 = evenLane ? v0 : e2;
      float t0 = evenLane ? e0 : v2;
      float k1 = evenLane ? v1 : e3;
      float t1 = evenLane ? e1 : v3;
      const int ra = evenLane ? 0 : 2;
      float ek0 = __expf(k0);
      float a0 = 1.0f / (1.0f + ek0);
      float g0 = (t0 >= 0.0f) ? (t0 + 0.5f) : (1.0f / (1.0f + __expf(-t0)));
      float b0 = (1.0f - a0) * g0;
      float ek1 = __expf(k1);
      float a1 = 1.0f / (1.0f + ek1);
      float g1 = (t1 >= 0.0f) ? (t1 + 0.5f) : (1.0f / (1.0f + __expf(-t1)));
      float b1 = (1.0f - a1) * g1;
      unsigned int w0 = ((unsigned int)__builtin_bit_cast(unsigned short, (_Float16)b0) << 16)
                        | (unsigned int)__builtin_bit_cast(unsigned short, (_Float16)a0);
      unsigned int w1 = ((unsigned int)__builtin_bit_cast(unsigned short, (_Float16)b1) << 16)
                        | (unsigned int)__builtin_bit_cast(unsigned short, (_Float16)a1);
      AB[(size_t)(row + ra) * 1024 + ch] = w0;
      AB[(size_t)(row + ra + 1) * 1024 + ch] = w1;
    }
  }
}

// ---------------- scan passes (fp16 unpack + FMA, 1 thread per channel) ----------------
__device__ __forceinline__ void unpack_ab(unsigned int v, float& a, float& b) {
  a = (float)__builtin_bit_cast(_Float16, (unsigned short)(v & 0xffffu));
  b = (float)__builtin_bit_cast(_Float16, (unsigned short)(v >> 16));
}

// Pass 1: per-chunk summary. 262144 threads: t -> ch (0..4095), c (0..NC-1).
__global__ void pass1_summary(const unsigned int* __restrict__ AB,
                              float* __restrict__ SA, float* __restrict__ SB) {
  int t = blockIdx.x * 256 + threadIdx.x;
  int ch = t & 4095, c = t >> 12;
  int bb = ch >> 10, hch = ch & 1023;
  const unsigned int* p = AB + (size_t)(bb * 4096 + c * CL) * 1024 + hch;
  float A = 1.0f, L = 0.0f;
#pragma unroll 8
  for (int i = 0; i < CL; ++i) {
    float a, b;
    unpack_ab(p[(size_t)i * 1024], a, b);
    A *= a;
    L = a * L + b;
  }
  SA[c * 4096 + ch] = A;
  SB[c * 4096 + ch] = L;
}

// Pass 2: sequential scan over NC chunk summaries; emits h entering each chunk.
__global__ void pass2_chunkscan(const float* __restrict__ SA, const float* __restrict__ SB,
                                float* __restrict__ Hin) {
  int ch = blockIdx.x * 256 + threadIdx.x;    // 4096 threads
  float h = 0.5f;                              // h_0 = g(0) = 0.5
  for (int c = 0; c < NC; ++c) {
    Hin[c * 4096 + ch] = h;
    h = SA[c * 4096 + ch] * h + SB[c * 4096 + ch];
  }
}

// Pass 3: re-walk chunk with correct h_in, emit h.
// MODE 0: bf16 h1 (layer-2 GEMM input) + fp32 h_n row. MODE 1: fp32 h2 to d_out + h_n row.
template <int MODE>
__global__ void pass3_emit(const unsigned int* __restrict__ AB, const float* __restrict__ Hin,
                           unsigned short* __restrict__ h1b, float* __restrict__ out,
                           float* __restrict__ hn) {
  int t = blockIdx.x * 256 + threadIdx.x;
  int ch = t & 4095, c = t >> 12;
  int bb = ch >> 10, hch = ch & 1023;
  const unsigned int* p = AB + (size_t)(bb * 4096 + c * CL) * 1024 + hch;
  float h = Hin[c * 4096 + ch];
#pragma unroll 8
  for (int i = 0; i < CL; ++i) {
    float a, b;
    unpack_ab(p[(size_t)i * 1024], a, b);
    h = a * h + b;
    size_t row = (size_t)(bb * 4096 + c * CL + i);
    if (MODE == 0) {
      h1b[row * 1024 + hch] = __builtin_bit_cast(unsigned short, (__bf16)h);
    } else {
      out[row * 1024 + hch] = h;
    }
  }
  if (c == NC - 1) hn[bb * 1024 + hch] = h;   // h at s = S-1
}

// ---------------- launcher ----------------
extern "C" void kernel_launch(void* const* d_in, const int* in_sizes, int n_in,
                              void* d_out, int out_size, void* d_ws, size_t ws_size,
                              hipStream_t stream) {
  const float* x   = (const float*)d_in[0];
  const float* Wz0 = (const float*)d_in[1];
  const float* bz0 = (const float*)d_in[2];
  const float* Wh0 = (const float*)d_in[3];
  const float* bh0 = (const float*)d_in[4];
  const float* Wz1 = (const float*)d_in[5];
  const float* bz1 = (const float*)d_in[6];
  const float* Wh1 = (const float*)d_in[7];
  const float* bh1 = (const float*)d_in[8];
  float* out = (float*)d_out;

  char* ws = (char*)d_ws;
  unsigned int* AB  = (unsigned int*)(ws);              // 16384*1024*4 = 64 MB
  __bf16*       XB  = (__bf16*)(ws + 67108864);         // 32 MB (x bf16, then h1 bf16)
  __bf16*       WC0 = (__bf16*)(ws + 100663296);        // 4 MB interleaved
  __bf16*       WC1 = (__bf16*)(ws + 104857600);        // 4 MB interleaved
  float*        SA  = (float*)(ws + 109051904);         // NC*4096*4 = 1 MB
  float*        SB  = (float*)(ws + 111149056);         // 1 MB
  float*        Hin = (float*)(ws + 113246208);         // 1 MB

  float* hn0 = out + 16777216;          // h_n[0] = h1[:, -1, :]
  float* hn1 = out + 16777216 + 4096;   // h_n[1] = h2[:, -1, :]

  // conversions to bf16
  cvt_f32_bf16<<<16384, 256, 0, stream>>>(x, (unsigned short*)XB, 4194304);
  cvt_w_interleave<<<2048, 256, 0, stream>>>(Wz0, Wh0, (unsigned short*)WC0);
  cvt_w_interleave<<<2048, 256, 0, stream>>>(Wz1, Wh1, (unsigned short*)WC1);

  // ---- layer 1 ----
  gemm_ab<<<dim3(128, 16), 256, 0, stream>>>(XB, WC0, bz0, bh0, AB);
  pass1_summary<<<1024, 256, 0, stream>>>(AB, SA, SB);
  pass2_chunkscan<<<16, 256, 0, stream>>>(SA, SB, Hin);
  pass3_emit<0><<<1024, 256, 0, stream>>>(AB, Hin, (unsigned short*)XB, nullptr, hn0);

  // ---- layer 2 ----
  gemm_ab<<<dim3(128, 16), 256, 0, stream>>>(XB, WC1, bz1, bh1, AB);
  pass1_summary<<<1024, 256, 0, stream>>>(AB, SA, SB);
  pass2_chunkscan<<<16, 256, 0, stream>>>(SA, SB, Hin);
  pass3_emit<1><<<1024, 256, 0, stream>>>(AB, Hin, nullptr, out, hn1);
}

// Round 8
// 382.819 us; speedup vs baseline: 1.4277x; 1.0231x over previous
//
#include <hip/hip_runtime.h>
#include <hip/hip_bf16.h>
#include <cstdint>
#include <cstddef>

// ---------------- types ----------------
typedef float f32x4v __attribute__((ext_vector_type(4)));
typedef __bf16 bf16x8 __attribute__((ext_vector_type(8)));
typedef unsigned short u16x4 __attribute__((ext_vector_type(4)));

#define GAS1(p) ((__attribute__((address_space(1))) void*)(p))
#define LAS3(p) ((__attribute__((address_space(3))) void*)(p))

// B=4, S=4096, D=H=1024. M = B*S = 16384.
// W layout: [2048][1024] bf16, rows 0..1023 = Wz, rows 1024..2047 = Wh.
// Each GEMM block: 128 rows x 64 channels, computing BOTH A*Wz^T and A*Wh^T tiles
// (acc_z + acc_h, 64 regs total). Epilogue: gate math per (k,th) in-lane, zero shuffles.
// AB layout: [M][1024] packed fp16 pairs: lo16 = a = 1-sigmoid(k), hi16 = b = sigmoid(k)*g(th).
// Scan: NC=64 chunks of CL=64 steps per sequence (S=4096).
#define NC 64
#define CL 64

// ---------------- fp32 -> bf16 conversion ----------------
__global__ void cvt_f32_bf16(const float* __restrict__ src,
                             unsigned short* __restrict__ dst, int n4) {
  int i = blockIdx.x * blockDim.x + threadIdx.x;
  if (i >= n4) return;
  float4 v = reinterpret_cast<const float4*>(src)[i];
  u16x4 o;
  o[0] = __builtin_bit_cast(unsigned short, (__bf16)v.x);
  o[1] = __builtin_bit_cast(unsigned short, (__bf16)v.y);
  o[2] = __builtin_bit_cast(unsigned short, (__bf16)v.z);
  o[3] = __builtin_bit_cast(unsigned short, (__bf16)v.w);
  reinterpret_cast<u16x4*>(dst)[i] = o;
}

// two fp32 sources -> one contiguous bf16 dest (Wz then Wh), n4h float4s each
__global__ void cvt_pair_bf16(const float* __restrict__ s0, const float* __restrict__ s1,
                              unsigned short* __restrict__ dst, int n4h) {
  int i = blockIdx.x * blockDim.x + threadIdx.x;
  if (i >= 2 * n4h) return;
  const float* s = (i < n4h) ? s0 : s1;
  int j = (i < n4h) ? i : i - n4h;
  float4 v = reinterpret_cast<const float4*>(s)[j];
  u16x4 o;
  o[0] = __builtin_bit_cast(unsigned short, (__bf16)v.x);
  o[1] = __builtin_bit_cast(unsigned short, (__bf16)v.y);
  o[2] = __builtin_bit_cast(unsigned short, (__bf16)v.z);
  o[3] = __builtin_bit_cast(unsigned short, (__bf16)v.w);
  reinterpret_cast<u16x4*>(dst)[i] = o;
}

// ---------------- bf16 MFMA GEMM (m97 structure) + split-acc fused gate epilogue ----------------
// A: [M][1024] bf16. W: [2048][1024] bf16 ([Wz;Wh]). Output: AB [M][1024] u32 (a,b fp16).
// 128 rows x 64 channels per block; 4 waves in 2x2 quadrants (64 rows x 32 ch each);
// BK=32; acc_z[4][2] + acc_h[4][2].
__global__ __launch_bounds__(256) void gemm_ab(
    const __bf16* __restrict__ A, const __bf16* __restrict__ W,
    const float* __restrict__ bzv, const float* __restrict__ bhv,
    unsigned int* __restrict__ AB) {
  __shared__ __bf16 Als[128 * 32];
  __shared__ __bf16 Bls[128 * 32];   // rows 0-63: Wz tile; rows 64-127: Wh tile
  const int tid = threadIdx.x;
  const int w = tid >> 6, l = tid & 63;
  const int bm = blockIdx.x, bn = blockIdx.y;   // bn 0..15 (64-channel tiles)
  const int wr = w >> 1, wc = w & 1;

  f32x4v acc_z[4][2] = {};
  f32x4v acc_h[4][2] = {};

  const int r0 = tid >> 2;            // 0..63
  const int c0 = (tid & 3) * 8;
  const __bf16* ga0 = A + (size_t)(bm * 128 + r0) * 1024 + c0;
  const __bf16* ga1 = ga0 + (size_t)64 * 1024;
  const __bf16* gz0 = W + (size_t)(bn * 64 + r0) * 1024 + c0;            // Wz rows
  const __bf16* gh0 = W + (size_t)(1024 + bn * 64 + r0) * 1024 + c0;     // Wh rows
  __bf16* lsA0 = Als + w * 512;          // wave-uniform bases; HW adds lane*16B
  __bf16* lsA1 = Als + 2048 + w * 512;
  __bf16* lsB0 = Bls + w * 512;          // Wz -> rows 0-63
  __bf16* lsB1 = Bls + 2048 + w * 512;   // Wh -> rows 64-127

  const int lr = l & 15, lk = (l >> 4) * 8;

  for (int kt = 0; kt < 32; ++kt) {
    const int ko = kt * 32;
    __builtin_amdgcn_global_load_lds(GAS1(ga0 + ko), LAS3(lsA0), 16, 0, 0);
    __builtin_amdgcn_global_load_lds(GAS1(ga1 + ko), LAS3(lsA1), 16, 0, 0);
    __builtin_amdgcn_global_load_lds(GAS1(gz0 + ko), LAS3(lsB0), 16, 0, 0);
    __builtin_amdgcn_global_load_lds(GAS1(gh0 + ko), LAS3(lsB1), 16, 0, 0);
    asm volatile("s_waitcnt vmcnt(0)" ::: "memory");
    __syncthreads();

    bf16x8 af[4], bz[2], bh[2];
#pragma unroll
    for (int f = 0; f < 4; ++f)
      af[f] = *reinterpret_cast<const bf16x8*>(Als + (wr * 64 + f * 16 + lr) * 32 + lk);
#pragma unroll
    for (int n = 0; n < 2; ++n) {
      bz[n] = *reinterpret_cast<const bf16x8*>(Bls + (wc * 32 + n * 16 + lr) * 32 + lk);
      bh[n] = *reinterpret_cast<const bf16x8*>(Bls + (64 + wc * 32 + n * 16 + lr) * 32 + lk);
    }
#pragma unroll
    for (int m = 0; m < 4; ++m)
#pragma unroll
      for (int n = 0; n < 2; ++n) {
        acc_z[m][n] = __builtin_amdgcn_mfma_f32_16x16x32_bf16(af[m], bz[n], acc_z[m][n], 0, 0, 0);
        acc_h[m][n] = __builtin_amdgcn_mfma_f32_16x16x32_bf16(af[m], bh[n], acc_h[m][n], 0, 0, 0);
      }
    __syncthreads();
  }

  // Epilogue: C/D layout col = lane&15, row = (lane>>4)*4 + reg (m89-verified).
  // k and th for channel ch are in the SAME lane/reg (acc_z vs acc_h) -> no shuffles.
  const int lg = l >> 4;
#pragma unroll
  for (int m = 0; m < 4; ++m) {
    const int row = bm * 128 + wr * 64 + m * 16 + lg * 4;
#pragma unroll
    for (int n = 0; n < 2; ++n) {
      const int ch = bn * 64 + wc * 32 + n * 16 + lr;   // global channel 0..1023
      const float kb = bzv[ch];
      const float tb = bhv[ch];
#pragma unroll
      for (int r = 0; r < 4; ++r) {
        float k = acc_z[m][n][r] + kb;
        float t = acc_h[m][n][r] + tb;
        float ek = __expf(k);
        float a = 1.0f / (1.0f + ek);        // 1 - sigmoid(k)
        float g = (t >= 0.0f) ? (t + 0.5f) : (1.0f / (1.0f + __expf(-t)));
        float bq = (1.0f - a) * g;
        unsigned int pw = ((unsigned int)__builtin_bit_cast(unsigned short, (_Float16)bq) << 16)
                          | (unsigned int)__builtin_bit_cast(unsigned short, (_Float16)a);
        AB[(size_t)(row + r) * 1024 + ch] = pw;
      }
    }
  }
}

// ---------------- scan passes (fp16 unpack + FMA, 1 thread per channel) ----------------
__device__ __forceinline__ void unpack_ab(unsigned int v, float& a, float& b) {
  a = (float)__builtin_bit_cast(_Float16, (unsigned short)(v & 0xffffu));
  b = (float)__builtin_bit_cast(_Float16, (unsigned short)(v >> 16));
}

// Pass 1: per-chunk summary. 262144 threads: t -> ch (0..4095), c (0..NC-1).
__global__ void pass1_summary(const unsigned int* __restrict__ AB,
                              float* __restrict__ SA, float* __restrict__ SB) {
  int t = blockIdx.x * 256 + threadIdx.x;
  int ch = t & 4095, c = t >> 12;
  int bb = ch >> 10, hch = ch & 1023;
  const unsigned int* p = AB + (size_t)(bb * 4096 + c * CL) * 1024 + hch;
  float A = 1.0f, L = 0.0f;
#pragma unroll 8
  for (int i = 0; i < CL; ++i) {
    float a, b;
    unpack_ab(p[(size_t)i * 1024], a, b);
    A *= a;
    L = a * L + b;
  }
  SA[c * 4096 + ch] = A;
  SB[c * 4096 + ch] = L;
}

// Pass 2: sequential scan over NC chunk summaries; emits h entering each chunk.
__global__ void pass2_chunkscan(const float* __restrict__ SA, const float* __restrict__ SB,
                                float* __restrict__ Hin) {
  int ch = blockIdx.x * 256 + threadIdx.x;    // 4096 threads
  float h = 0.5f;                              // h_0 = g(0) = 0.5
  for (int c = 0; c < NC; ++c) {
    Hin[c * 4096 + ch] = h;
    h = SA[c * 4096 + ch] * h + SB[c * 4096 + ch];
  }
}

// Pass 3: re-walk chunk with correct h_in, emit h.
// MODE 0: bf16 h1 (layer-2 GEMM input) + fp32 h_n row. MODE 1: fp32 h2 to d_out + h_n row.
template <int MODE>
__global__ void pass3_emit(const unsigned int* __restrict__ AB, const float* __restrict__ Hin,
                           unsigned short* __restrict__ h1b, float* __restrict__ out,
                           float* __restrict__ hn) {
  int t = blockIdx.x * 256 + threadIdx.x;
  int ch = t & 4095, c = t >> 12;
  int bb = ch >> 10, hch = ch & 1023;
  const unsigned int* p = AB + (size_t)(bb * 4096 + c * CL) * 1024 + hch;
  float h = Hin[c * 4096 + ch];
#pragma unroll 8
  for (int i = 0; i < CL; ++i) {
    float a, b;
    unpack_ab(p[(size_t)i * 1024], a, b);
    h = a * h + b;
    size_t row = (size_t)(bb * 4096 + c * CL + i);
    if (MODE == 0) {
      h1b[row * 1024 + hch] = __builtin_bit_cast(unsigned short, (__bf16)h);
    } else {
      out[row * 1024 + hch] = h;
    }
  }
  if (c == NC - 1) hn[bb * 1024 + hch] = h;   // h at s = S-1
}

// ---------------- launcher ----------------
extern "C" void kernel_launch(void* const* d_in, const int* in_sizes, int n_in,
                              void* d_out, int out_size, void* d_ws, size_t ws_size,
                              hipStream_t stream) {
  const float* x   = (const float*)d_in[0];
  const float* Wz0 = (const float*)d_in[1];
  const float* bz0 = (const float*)d_in[2];
  const float* Wh0 = (const float*)d_in[3];
  const float* bh0 = (const float*)d_in[4];
  const float* Wz1 = (const float*)d_in[5];
  const float* bz1 = (const float*)d_in[6];
  const float* Wh1 = (const float*)d_in[7];
  const float* bh1 = (const float*)d_in[8];
  float* out = (float*)d_out;

  char* ws = (char*)d_ws;
  unsigned int* AB  = (unsigned int*)(ws);              // 16384*1024*4 = 64 MB
  __bf16*       XB  = (__bf16*)(ws + 67108864);         // 32 MB (x bf16, then h1 bf16)
  __bf16*       WC0 = (__bf16*)(ws + 100663296);        // 4 MB [Wz0;Wh0]
  __bf16*       WC1 = (__bf16*)(ws + 104857600);        // 4 MB [Wz1;Wh1]
  float*        SA  = (float*)(ws + 109051904);         // NC*4096*4 = 1 MB
  float*        SB  = (float*)(ws + 111149056);         // 1 MB
  float*        Hin = (float*)(ws + 113246208);         // 1 MB

  float* hn0 = out + 16777216;          // h_n[0] = h1[:, -1, :]
  float* hn1 = out + 16777216 + 4096;   // h_n[1] = h2[:, -1, :]

  // conversions to bf16
  cvt_f32_bf16<<<16384, 256, 0, stream>>>(x, (unsigned short*)XB, 4194304);
  cvt_pair_bf16<<<2048, 256, 0, stream>>>(Wz0, Wh0, (unsigned short*)WC0, 262144);
  cvt_pair_bf16<<<2048, 256, 0, stream>>>(Wz1, Wh1, (unsigned short*)WC1, 262144);

  // ---- layer 1 ----
  gemm_ab<<<dim3(128, 16), 256, 0, stream>>>(XB, WC0, bz0, bh0, AB);
  pass1_summary<<<1024, 256, 0, stream>>>(AB, SA, SB);
  pass2_chunkscan<<<16, 256, 0, stream>>>(SA, SB, Hin);
  pass3_emit<0><<<1024, 256, 0, stream>>>(AB, Hin, (unsigned short*)XB, nullptr, hn0);

  // ---- layer 2 ----
  gemm_ab<<<dim3(128, 16), 256, 0, stream>>>(XB, WC1, bz1, bh1, AB);
  pass1_summary<<<1024, 256, 0, stream>>>(AB, SA, SB);
  pass2_chunkscan<<<16, 256, 0, stream>>>(SA, SB, Hin);
  pass3_emit<1><<<1024, 256, 0, stream>>>(AB, Hin, nullptr, out, hn1);
}